// Round 1
// baseline (225.340 us; speedup 1.0000x reference)
//
#include <hip/hip_runtime.h>

// LIF spike recurrence over T axis.
// x: [B=32, T=8, C=128, H=32, W=32] fp32, out: same shape (0/1 spikes).
// mem = mem*0.5 + x_t; spike = (mem > 1.0); mem = spike ? 0 : mem.
//
// One thread = one float4 (4 contiguous W elements) of one neuron, full
// T-loop in registers. All 8 loads are address-independent -> compiler can
// keep them in flight; memory-bound kernel, target ~6 TB/s.

#define TT 8
#define INNER4 (128 * 32 * 32 / 4)   // C*H*W in float4 units = 32768

__global__ __launch_bounds__(256) void lif_kernel(
    const float4* __restrict__ x, float4* __restrict__ out) {
    int idx = blockIdx.x * blockDim.x + threadIdx.x;   // 0 .. B*INNER4-1
    int b = idx >> 15;          // idx / INNER4
    int i = idx & (INNER4 - 1); // idx % INNER4

    // Base offset (float4 units) for (b, t=0, i)
    int base = b * (TT * INNER4) + i;

    // Hoist all 8 loads (independent addresses)
    float4 xv[TT];
#pragma unroll
    for (int t = 0; t < TT; ++t) {
        xv[t] = x[base + t * INNER4];
    }

    float4 mem = make_float4(0.f, 0.f, 0.f, 0.f);
#pragma unroll
    for (int t = 0; t < TT; ++t) {
        float4 xt = xv[t];
        mem.x = mem.x * 0.5f + xt.x;
        mem.y = mem.y * 0.5f + xt.y;
        mem.z = mem.z * 0.5f + xt.z;
        mem.w = mem.w * 0.5f + xt.w;

        float4 sp;
        sp.x = (mem.x > 1.0f) ? 1.0f : 0.0f;
        sp.y = (mem.y > 1.0f) ? 1.0f : 0.0f;
        sp.z = (mem.z > 1.0f) ? 1.0f : 0.0f;
        sp.w = (mem.w > 1.0f) ? 1.0f : 0.0f;

        mem.x = (mem.x > 1.0f) ? 0.0f : mem.x;
        mem.y = (mem.y > 1.0f) ? 0.0f : mem.y;
        mem.z = (mem.z > 1.0f) ? 0.0f : mem.z;
        mem.w = (mem.w > 1.0f) ? 0.0f : mem.w;

        out[base + t * INNER4] = sp;
    }
}

extern "C" void kernel_launch(void* const* d_in, const int* in_sizes, int n_in,
                              void* d_out, int out_size, void* d_ws, size_t ws_size,
                              hipStream_t stream) {
    const float4* x = (const float4*)d_in[0];
    float4* out = (float4*)d_out;

    // total float4 work items: 32 (B) * 32768 (CHW/4) = 1,048,576
    const int total4 = 32 * INNER4;
    const int block = 256;
    const int grid = total4 / block;  // 4096
    lif_kernel<<<grid, block, 0, stream>>>(x, out);
}

// Round 2
// 217.760 us; speedup vs baseline: 1.0348x; 1.0348x over previous
//
#include <hip/hip_runtime.h>

// LIF spike recurrence over T axis.
// x: [B=32, T=8, C=128, H=32, W=32] fp32, out: same shape (0/1 spikes).
// mem = mem*0.5 + x_t; spike = (mem > 1.0); mem = spike ? 0 : mem.
//
// One thread = one float4 (4 contiguous W elements) of one neuron, full
// T-loop in registers. Streaming, zero-reuse kernel -> nontemporal
// loads/stores to bypass L2/L3 allocation (256 MB footprint would thrash
// the 256 MB L3 / 4 MB-per-XCD L2 otherwise).

#define TT 8
#define INNER4 (128 * 32 * 32 / 4)   // C*H*W in float4 units = 32768

typedef float v4f __attribute__((ext_vector_type(4)));

__global__ __launch_bounds__(256) void lif_kernel(
    const v4f* __restrict__ x, v4f* __restrict__ out) {
    int idx = blockIdx.x * blockDim.x + threadIdx.x;   // 0 .. B*INNER4-1
    int b = idx >> 15;          // idx / INNER4
    int i = idx & (INNER4 - 1); // idx % INNER4

    // Base offset (float4 units) for (b, t=0, i)
    int base = b * (TT * INNER4) + i;

    // Hoist all 8 loads (independent addresses, nontemporal)
    v4f xv[TT];
#pragma unroll
    for (int t = 0; t < TT; ++t) {
        xv[t] = __builtin_nontemporal_load(x + base + t * INNER4);
    }

    v4f mem = {0.f, 0.f, 0.f, 0.f};
#pragma unroll
    for (int t = 0; t < TT; ++t) {
        mem = mem * 0.5f + xv[t];

        v4f sp;
        sp.x = (mem.x > 1.0f) ? 1.0f : 0.0f;
        sp.y = (mem.y > 1.0f) ? 1.0f : 0.0f;
        sp.z = (mem.z > 1.0f) ? 1.0f : 0.0f;
        sp.w = (mem.w > 1.0f) ? 1.0f : 0.0f;

        mem.x = (mem.x > 1.0f) ? 0.0f : mem.x;
        mem.y = (mem.y > 1.0f) ? 0.0f : mem.y;
        mem.z = (mem.z > 1.0f) ? 0.0f : mem.z;
        mem.w = (mem.w > 1.0f) ? 0.0f : mem.w;

        __builtin_nontemporal_store(sp, out + base + t * INNER4);
    }
}

extern "C" void kernel_launch(void* const* d_in, const int* in_sizes, int n_in,
                              void* d_out, int out_size, void* d_ws, size_t ws_size,
                              hipStream_t stream) {
    const v4f* x = (const v4f*)d_in[0];
    v4f* out = (v4f*)d_out;

    // total float4 work items: 32 (B) * 32768 (CHW/4) = 1,048,576
    const int total4 = 32 * INNER4;
    const int block = 256;
    const int grid = total4 / block;  // 4096
    lif_kernel<<<grid, block, 0, stream>>>(x, out);
}